// Round 12
// baseline (146.866 us; speedup 1.0000x reference)
//
#include <hip/hip_runtime.h>
#include <hip/hip_bf16.h>
#include <float.h>

#define Bc 32
#define Nc 512
#define Dc 128
#define Hc 8
#define DKc 16
#define Ec 128
#define LOG2E 1.44269504088896340736f
#define SCLAMP 80.0f

typedef __attribute__((ext_vector_type(4))) short s16x4;
typedef __attribute__((ext_vector_type(8))) short s16x8;
typedef __attribute__((ext_vector_type(4))) float f32x4;

union BFU { __hip_bfloat16 b; short s; };
static __device__ inline short f2bf(float f) { BFU u; u.b = __float2bfloat16(f); return u.s; }
static __device__ inline s16x4 pack4(float a, float b, float c, float d) {
  s16x4 r; r[0] = f2bf(a); r[1] = f2bf(b); r[2] = f2bf(c); r[3] = f2bf(d); return r;
}

#if __has_builtin(__builtin_amdgcn_exp2f)
#define EXP2F(x) __builtin_amdgcn_exp2f(x)
#else
#define EXP2F(x) exp2f(x)
#endif

// D = A*B + C for 16x16x16 bf16. A[m=l&15][k=(l>>4)*4+i]; B[k=(l>>4)*4+i][n=l&15];
// C/D: col(n)=l&15, row(m)=(l>>4)*4+reg.
static __device__ inline f32x4 mfma16(s16x4 a, s16x4 b, f32x4 c) {
#if __has_builtin(__builtin_amdgcn_mfma_f32_16x16x16bf16_1k)
  return __builtin_amdgcn_mfma_f32_16x16x16bf16_1k(a, b, c, 0, 0, 0);
#else
  int lane = threadIdx.x & 63;
  int g = lane >> 4, base = lane & 15;
  int src0 = (base + 32 * g) & 63;
  int src1 = (base + 32 * g + 16) & 63;
  int ax = ((int*)&a)[0], ay = ((int*)&a)[1];
  int bx = ((int*)&b)[0], by = ((int*)&b)[1];
  int A0 = __shfl(ax, src0), A1 = __shfl(ay, src0);
  int A2 = __shfl(ax, src1), A3 = __shfl(ay, src1);
  int B0 = __shfl(bx, src0), B1 = __shfl(by, src0);
  int B2 = __shfl(bx, src1), B3 = __shfl(by, src1);
  if (g >= 2) { A0 = A1 = A2 = A3 = 0; B0 = B1 = B2 = B3 = 0; }
  s16x8 A8, B8;
  ((int*)&A8)[0] = A0; ((int*)&A8)[1] = A1; ((int*)&A8)[2] = A2; ((int*)&A8)[3] = A3;
  ((int*)&B8)[0] = B0; ((int*)&B8)[1] = B1; ((int*)&B8)[2] = B2; ((int*)&B8)[3] = B3;
  return __builtin_amdgcn_mfma_f32_16x16x32_bf16(A8, B8, c, 0, 0, 0);
#endif
}

// ---- prep: weight conv (0..255) + mask detector (256) + 1024-cell table (257..260) ----
// tabI[h*1024 + c] = (bf16(f(mid)*L)<<16) | bf16(a*L); cells over [-8,8), width 1/64.
__global__ __launch_bounds__(256) void prep_all(
    const float* __restrict__ Wq, const float* __restrict__ Wk, const float* __restrict__ Wv,
    const float* __restrict__ Wo,
    const unsigned char* __restrict__ m, int* __restrict__ flag,
    const float* __restrict__ mW1, const float* __restrict__ mb1,
    const float* __restrict__ mW2, const float* __restrict__ mb2,
    const float* __restrict__ mW3, const float* __restrict__ mb3,
    short* __restrict__ Wt, short* __restrict__ Wob, int* __restrict__ tabI)
{
  int blk = blockIdx.x;
  int t = threadIdx.x;

  if (blk == 256) {   // mask-format detector (single-writer)
    __shared__ int red[4];
    int any = 0;
    for (int u = t; u < 16384; u += 256)
      if ((u & 3) != 0 && m[u] != 0) any = 1;
    unsigned long long bal = __ballot(any != 0);
    if ((t & 63) == 0) red[t >> 6] = (bal != 0ULL) ? 1 : 0;
    __syncthreads();
    if (t == 0) *flag = red[0] | red[1] | red[2] | red[3];
    return;
  }

  if (blk >= 257) {   // cell table: exact MLP tangent-segment at cell midpoint
    __shared__ float wl[440];
    for (int u = t; u < 440; u += 256) {
      float v;
      if (u < 16) v = mW1[u];
      else if (u < 32)  v = mb1[u - 16];
      else if (u < 288) v = mW2[u - 32];
      else if (u < 304) v = mb2[u - 288];
      else if (u < 432) v = mW3[u - 304];
      else v = mb3[u - 432];
      wl[u] = v;
    }
    __syncthreads();
    int c = (blk - 257) * 256 + t;                       // 0..1023
    float mm = fmaf((float)c, 0.015625f, -7.9921875f);   // -8 + 1/128 + c/64

    float pre[16];
    #pragma unroll
    for (int u = 0; u < 16; ++u) pre[u] = fmaf(mm, wl[u], wl[16 + u]);
    float a2[16], v2[16];
    #pragma unroll
    for (int v = 0; v < 16; ++v) { a2[v] = 0.f; v2[v] = wl[288 + v]; }
    #pragma unroll
    for (int u = 0; u < 16; ++u) {
      bool act = pre[u] > 0.f;
      float w1 = act ? wl[u] : 0.f;
      float pp = act ? pre[u] : 0.f;
      #pragma unroll
      for (int v = 0; v < 16; ++v) {
        float w2 = wl[32 + u * 16 + v];
        a2[v] = fmaf(w1, w2, a2[v]);
        v2[v] = fmaf(pp, w2, v2[v]);
      }
    }
    float ah[8], fh[8];
    #pragma unroll
    for (int h = 0; h < 8; ++h) { ah[h] = 0.f; fh[h] = wl[432 + h]; }
    #pragma unroll
    for (int v = 0; v < 16; ++v) {
      bool act = v2[v] > 0.f;
      float av = act ? a2[v] : 0.f;
      float vv = act ? v2[v] : 0.f;
      #pragma unroll
      for (int h = 0; h < 8; ++h) {
        float w3 = wl[304 + v * 8 + h];
        ah[h] = fmaf(av, w3, ah[h]);
        fh[h] = fmaf(vv, w3, fh[h]);
      }
    }
    #pragma unroll
    for (int h = 0; h < 8; ++h) {
      int ab = (int)(unsigned short)(f2bf(ah[h] * LOG2E));
      int fb = ((int)f2bf(fh[h] * LOG2E)) << 16;
      tabI[h * 1024 + c] = fb | ab;                      // head-major for b32 LDS gather
    }
    return;
  }

  int o = blk * 256 + t;
  if (o < 49152) {
    int mat = o >> 14, r = o & 16383;
    int hk = r >> 7, d = r & 127;
    const float* src = (mat == 0) ? Wq : ((mat == 1) ? Wk : Wv);
    Wt[o] = f2bf(src[(hk >> 4) * 2048 + d * 16 + (hk & 15)]);
  } else {
    int o2 = o - 49152;
    int et = o2 >> 11, s = (o2 >> 8) & 7, lane = (o2 >> 2) & 63, i = o2 & 3;
    Wob[o2] = f2bf(Wo[(s * 16 + (lane >> 4) * 4 + i) * 128 + et * 16 + (lane & 15)]);
  }
}

// ---- kernel A: QKV projection via MFMA (unchanged, verified) ----
__global__ __launch_bounds__(256, 4) void qkv4(
    const float* __restrict__ q, const short* __restrict__ Wt,
    short* __restrict__ Qb, short* __restrict__ Kb, short* __restrict__ Vt)
{
  __shared__ short qs[16][136];
  int blk = blockIdx.x;
  int b = blk >> 5;
  int rt = (blk & 31) << 4;
  int t = threadIdx.x;
  int wid = t >> 6, lane = t & 63;
  int lq = lane & 15, lg = lane >> 4;

  #pragma unroll
  for (int it = 0; it < 2; ++it) {
    int u = t + it * 256;
    int row = u >> 5, c4 = (u & 31) << 2;
    float4 v = *(const float4*)&q[((((b << 9) + rt + row) << 7)) + c4];
    *(s16x4*)&qs[row][c4] = pack4(v.x, v.y, v.z, v.w);
  }
  __syncthreads();

  s16x4 af[8];
  #pragma unroll
  for (int ks = 0; ks < 8; ++ks)
    af[ks] = *(const s16x4*)&qs[lq][ks * 16 + lg * 4];

  #pragma unroll 1
  for (int pj = 0; pj < 3; ++pj) {
    const short* Wm = Wt + pj * 16384;
    #pragma unroll
    for (int c2 = 0; c2 < 2; ++c2) {
      int ct = wid * 2 + c2;
      f32x4 acc = (f32x4)0.f;
      #pragma unroll
      for (int ks = 0; ks < 8; ++ks) {
        s16x4 bf = *(const s16x4*)&Wm[(ct * 16 + lq) * 128 + ks * 16 + lg * 4];
        acc = mfma16(af[ks], bf, acc);
      }
      if (pj == 0) {
        s16x4 pk = pack4(acc[0] * (0.25f * LOG2E), acc[1] * (0.25f * LOG2E),
                         acc[2] * (0.25f * LOG2E), acc[3] * (0.25f * LOG2E));
        #pragma unroll
        for (int r = 0; r < 4; ++r)
          Qb[(ct << 18) + (b << 13) + ((rt + lg * 4 + r) << 4) + lq] = pk[r];
      } else if (pj == 1) {
        s16x4 pk = pack4(acc[0], acc[1], acc[2], acc[3]);
        #pragma unroll
        for (int r = 0; r < 4; ++r)
          Kb[(ct << 18) + (b << 13) + ((rt + lg * 4 + r) << 4) + lq] = pk[r];
      } else {
        s16x4 pk = pack4(acc[0], acc[1], acc[2], acc[3]);
        *(s16x4*)&Vt[(ct << 18) + (((b << 4) + lq) << 9) + rt + lg * 4] = pk;
      }
    }
  }
}

// ---- kernel B: 8-wave attn, WAVE = HEAD. LDS 32768B: tab int[8][1024];
// wave h's slice [h<<12 .. ) is overlaid by its obf (512B) after its main loop.
// Persistent state per wave ~11 VGPR -> compiler has headroom to pipeline chunks.
__global__ __launch_bounds__(512, 4) void attn12(
    const float* __restrict__ edge, const unsigned char* __restrict__ maskB,
    const int* __restrict__ flag,
    const short* __restrict__ Qb, const short* __restrict__ Kb, const short* __restrict__ Vt,
    const short* __restrict__ Wob,
    const int* __restrict__ tabI,
    float* __restrict__ out)
{
  __shared__ __align__(16) char smem[32768];

  int t = threadIdx.x;
  int wid = t >> 6, lane = t & 63;      // wid = head
  int lq = lane & 15, lg = lane >> 4;
  int b = blockIdx.x >> 5;
  int qt = (blockIdx.x & 31) << 4;
  int mflag = *flag;

  int* tabH = (int*)smem + (wid << 10);     // this wave's 4KB head slice

  // stage table (8192 ints = 2048 int4)
  for (int u = t; u < 2048; u += 512)
    ((int4*)smem)[u] = ((const int4*)tabI)[u];

  const short* Kl = Kb + (wid << 18) + (b << 13) + (lq << 4) + (lg << 2);
  const short* Vl = Vt + (wid << 18) + (((b << 4) + lq) << 9) + (lg << 2);
  const short* Ql = Qb + (wid << 18) + (b << 13) + ((qt + lq) << 4) + (lg << 2);
  unsigned mbase = (((b << 9) + qt + lq) << 9) + (lg << 2);

  s16x4 qf = *(const s16x4*)Ql;
  f32x4 oacc = (f32x4)0.f;
  float psum = 0.f;

  // prologue: chunk 0 edge + mask
  float4 ev = *(const float4*)&edge[mbase];
  int4 mkv;
  if (mflag) {
    uchar4 u = *(const uchar4*)&maskB[mbase];
    mkv.x = u.x; mkv.y = u.y; mkv.z = u.z; mkv.w = u.w;
  } else {
    mkv = *(const int4*)&((const int*)maskB)[mbase];
  }

  __syncthreads();   // table staged

  #pragma unroll 2
  for (int cc = 0; cc < 32; ++cc) {
    int jb = cc << 4;

    // cell index + in-cell offset for this lane's 4 edges (q=lq, j=jb+lg*4+r)
    float fx0 = fminf(fmaxf(fmaf(ev.x, 64.f, 512.f), 0.f), 1023.f);
    float fx1 = fminf(fmaxf(fmaf(ev.y, 64.f, 512.f), 0.f), 1023.f);
    float fx2 = fminf(fmaxf(fmaf(ev.z, 64.f, 512.f), 0.f), 1023.f);
    float fx3 = fminf(fmaxf(fmaf(ev.w, 64.f, 512.f), 0.f), 1023.f);
    int ix0 = (int)fx0, ix1 = (int)fx1, ix2 = (int)fx2, ix3 = (int)fx3;
    float em0 = ev.x - fmaf((float)ix0, 0.015625f, -7.9921875f);
    float em1 = ev.y - fmaf((float)ix1, 0.015625f, -7.9921875f);
    float em2 = ev.z - fmaf((float)ix2, 0.015625f, -7.9921875f);
    float em3 = ev.w - fmaf((float)ix3, 0.015625f, -7.9921875f);

    int c0 = tabH[ix0], c1 = tabH[ix1], c2 = tabH[ix2], c3 = tabH[ix3];
    s16x4 kf = *(const s16x4*)(Kl + (jb << 4));
    s16x4 vf = *(const s16x4*)(Vl + jb);

    // prefetch next chunk's edge + mask
    float4 evn; int4 mkn;
    if (cc < 31) {
      int jbn = (cc + 1) << 4;
      evn = *(const float4*)&edge[mbase + jbn];
      if (mflag) {
        uchar4 u = *(const uchar4*)&maskB[mbase + jbn];
        mkn.x = u.x; mkn.y = u.y; mkn.z = u.z; mkn.w = u.w;
      } else {
        mkn = *(const int4*)&((const int*)maskB)[mbase + jbn];
      }
    } else { evn = ev; mkn = mkv; }

    f32x4 sc;
    sc[0] = fmaf(__int_as_float(c0 << 16), em0, __int_as_float(c0 & 0xffff0000));
    sc[1] = fmaf(__int_as_float(c1 << 16), em1, __int_as_float(c1 & 0xffff0000));
    sc[2] = fmaf(__int_as_float(c2 << 16), em2, __int_as_float(c2 & 0xffff0000));
    sc[3] = fmaf(__int_as_float(c3 << 16), em3, __int_as_float(c3 & 0xffff0000));
    sc = mfma16(kf, qf, sc);
    float p0 = mkv.x ? 0.f : EXP2F(fminf(sc[0], SCLAMP));
    float p1 = mkv.y ? 0.f : EXP2F(fminf(sc[1], SCLAMP));
    float p2 = mkv.z ? 0.f : EXP2F(fminf(sc[2], SCLAMP));
    float p3 = mkv.w ? 0.f : EXP2F(fminf(sc[3], SCLAMP));
    psum += (p0 + p1) + (p2 + p3);
    s16x4 pf = pack4(p0, p1, p2, p3);
    oacc = mfma16(vf, pf, oacc);

    ev = evn; mkv = mkn;
  }

  // ---- epilogue ----
  // full row-sum for q=lq within this wave (head fully owned by wave)
  float s = psum;
  s += __shfl_xor(s, 16);
  s += __shfl_xor(s, 32);
  float inv = (s > 0.f) ? 1.f / s : 0.f;

  // normalized O^T fragment -> overlay own table slice (safe: only this wave reads it)
  *(s16x4*)(smem + (wid << 12) + lane * 8) =
      pack4(oacc[0] * inv, oacc[1] * inv, oacc[2] * inv, oacc[3] * inv);
  __syncthreads();

  // out-projection: wave wid computes e-tile et=wid: d2 = sum_s Wo_frag[wid][s] x obf[s]
  {
    f32x4 d2a = (f32x4)0.f;
    #pragma unroll
    for (int s8 = 0; s8 < 8; ++s8) {
      s16x4 ob = *(const s16x4*)(smem + (s8 << 12) + lane * 8);
      s16x4 wo = *(const s16x4*)&Wob[(((wid << 3) + s8) << 8) + (lane << 2)];
      d2a = mfma16(wo, ob, d2a);
    }
    *(float4*)&out[((((b << 9) + qt + lq) << 7)) + (wid << 4) + (lg << 2)] =
        *(float4*)&d2a;
  }
}

extern "C" void kernel_launch(void* const* d_in, const int* in_sizes, int n_in,
                              void* d_out, int out_size, void* d_ws, size_t ws_size,
                              hipStream_t stream)
{
  const float* q    = (const float*)d_in[0];
  const unsigned char* mask = (const unsigned char*)d_in[1];
  const float* edge = (const float*)d_in[2];
  const float* Wq   = (const float*)d_in[3];
  const float* Wk   = (const float*)d_in[4];
  const float* Wv   = (const float*)d_in[5];
  const float* Wo   = (const float*)d_in[6];
  const float* mW1  = (const float*)d_in[7];
  const float* mb1  = (const float*)d_in[8];
  const float* mW2  = (const float*)d_in[9];
  const float* mb2  = (const float*)d_in[10];
  const float* mW3  = (const float*)d_in[11];
  const float* mb3  = (const float*)d_in[12];
  float* out = (float*)d_out;

  size_t per = (size_t)Hc * Bc * Nc * DKc;     // 2,097,152 bf16 elems per matrix
  short* Wt  = (short*)d_ws;                   // 49152
  short* Wob = Wt + 49152;                     // 16384
  short* Qb  = Wob + 16384;
  short* Kb  = Qb + per;
  short* Vt  = Kb + per;
  int* tabI  = (int*)(Vt + per);               // 8192 ints (32 KB), 16B-aligned
  int* flag  = tabI + 8192;                    // ~12.7 MB used

  prep_all<<<dim3(261), dim3(256), 0, stream>>>(Wq, Wk, Wv, Wo, mask, flag,
      mW1, mb1, mW2, mb2, mW3, mb3, Wt, Wob, tabI);
  qkv4<<<dim3(Bc * 32), dim3(256), 0, stream>>>(q, Wt, Qb, Kb, Vt);
  attn12<<<dim3(Bc * 32), dim3(512), 0, stream>>>(edge, mask, flag, Qb, Kb, Vt, Wob,
      tabI, out);
}

// Round 13
// 117.549 us; speedup vs baseline: 1.2494x; 1.2494x over previous
//
#include <hip/hip_runtime.h>
#include <hip/hip_bf16.h>
#include <float.h>

#define Bc 32
#define Nc 512
#define Dc 128
#define Hc 8
#define DKc 16
#define Ec 128
#define LOG2E 1.44269504088896340736f
#define SCLAMP 80.0f

typedef __attribute__((ext_vector_type(4))) short s16x4;
typedef __attribute__((ext_vector_type(8))) short s16x8;
typedef __attribute__((ext_vector_type(4))) float f32x4;

union BFU { __hip_bfloat16 b; short s; };
static __device__ inline short f2bf(float f) { BFU u; u.b = __float2bfloat16(f); return u.s; }
static __device__ inline s16x4 pack4(float a, float b, float c, float d) {
  s16x4 r; r[0] = f2bf(a); r[1] = f2bf(b); r[2] = f2bf(c); r[3] = f2bf(d); return r;
}

#if __has_builtin(__builtin_amdgcn_exp2f)
#define EXP2F(x) __builtin_amdgcn_exp2f(x)
#else
#define EXP2F(x) exp2f(x)
#endif

// D = A*B + C for 16x16x16 bf16. A[m=l&15][k=(l>>4)*4+i]; B[k=(l>>4)*4+i][n=l&15];
// C/D: col(n)=l&15, row(m)=(l>>4)*4+reg.
static __device__ inline f32x4 mfma16(s16x4 a, s16x4 b, f32x4 c) {
#if __has_builtin(__builtin_amdgcn_mfma_f32_16x16x16bf16_1k)
  return __builtin_amdgcn_mfma_f32_16x16x16bf16_1k(a, b, c, 0, 0, 0);
#else
  int lane = threadIdx.x & 63;
  int g = lane >> 4, base = lane & 15;
  int src0 = (base + 32 * g) & 63;
  int src1 = (base + 32 * g + 16) & 63;
  int ax = ((int*)&a)[0], ay = ((int*)&a)[1];
  int bx = ((int*)&b)[0], by = ((int*)&b)[1];
  int A0 = __shfl(ax, src0), A1 = __shfl(ay, src0);
  int A2 = __shfl(ax, src1), A3 = __shfl(ay, src1);
  int B0 = __shfl(bx, src0), B1 = __shfl(by, src0);
  int B2 = __shfl(bx, src1), B3 = __shfl(by, src1);
  if (g >= 2) { A0 = A1 = A2 = A3 = 0; B0 = B1 = B2 = B3 = 0; }
  s16x8 A8, B8;
  ((int*)&A8)[0] = A0; ((int*)&A8)[1] = A1; ((int*)&A8)[2] = A2; ((int*)&A8)[3] = A3;
  ((int*)&B8)[0] = B0; ((int*)&B8)[1] = B1; ((int*)&B8)[2] = B2; ((int*)&B8)[3] = B3;
  return __builtin_amdgcn_mfma_f32_16x16x32_bf16(A8, B8, c, 0, 0, 0);
#endif
}

// ---- prep: weight conv (0..255) + mask detector (256) + 1024-cell table (257..260) ----
// tabI[h*1024 + c] = (bf16(f(mid)*L)<<16) | bf16(a*L); cells over [-8,8), width 1/64.
__global__ __launch_bounds__(256) void prep_all(
    const float* __restrict__ Wq, const float* __restrict__ Wk, const float* __restrict__ Wv,
    const float* __restrict__ Wo,
    const unsigned char* __restrict__ m, int* __restrict__ flag,
    const float* __restrict__ mW1, const float* __restrict__ mb1,
    const float* __restrict__ mW2, const float* __restrict__ mb2,
    const float* __restrict__ mW3, const float* __restrict__ mb3,
    short* __restrict__ Wt, short* __restrict__ Wob, int* __restrict__ tabI)
{
  int blk = blockIdx.x;
  int t = threadIdx.x;

  if (blk == 256) {   // mask-format detector (single-writer)
    __shared__ int red[4];
    int any = 0;
    for (int u = t; u < 16384; u += 256)
      if ((u & 3) != 0 && m[u] != 0) any = 1;
    unsigned long long bal = __ballot(any != 0);
    if ((t & 63) == 0) red[t >> 6] = (bal != 0ULL) ? 1 : 0;
    __syncthreads();
    if (t == 0) *flag = red[0] | red[1] | red[2] | red[3];
    return;
  }

  if (blk >= 257) {   // cell table: exact MLP tangent-segment at cell midpoint
    __shared__ float wl[440];
    for (int u = t; u < 440; u += 256) {
      float v;
      if (u < 16) v = mW1[u];
      else if (u < 32)  v = mb1[u - 16];
      else if (u < 288) v = mW2[u - 32];
      else if (u < 304) v = mb2[u - 288];
      else if (u < 432) v = mW3[u - 304];
      else v = mb3[u - 432];
      wl[u] = v;
    }
    __syncthreads();
    int c = (blk - 257) * 256 + t;                       // 0..1023
    float mm = fmaf((float)c, 0.015625f, -7.9921875f);   // -8 + 1/128 + c/64

    float pre[16];
    #pragma unroll
    for (int u = 0; u < 16; ++u) pre[u] = fmaf(mm, wl[u], wl[16 + u]);
    float a2[16], v2[16];
    #pragma unroll
    for (int v = 0; v < 16; ++v) { a2[v] = 0.f; v2[v] = wl[288 + v]; }
    #pragma unroll
    for (int u = 0; u < 16; ++u) {
      bool act = pre[u] > 0.f;
      float w1 = act ? wl[u] : 0.f;
      float pp = act ? pre[u] : 0.f;
      #pragma unroll
      for (int v = 0; v < 16; ++v) {
        float w2 = wl[32 + u * 16 + v];
        a2[v] = fmaf(w1, w2, a2[v]);
        v2[v] = fmaf(pp, w2, v2[v]);
      }
    }
    float ah[8], fh[8];
    #pragma unroll
    for (int h = 0; h < 8; ++h) { ah[h] = 0.f; fh[h] = wl[432 + h]; }
    #pragma unroll
    for (int v = 0; v < 16; ++v) {
      bool act = v2[v] > 0.f;
      float av = act ? a2[v] : 0.f;
      float vv = act ? v2[v] : 0.f;
      #pragma unroll
      for (int h = 0; h < 8; ++h) {
        float w3 = wl[304 + v * 8 + h];
        ah[h] = fmaf(av, w3, ah[h]);
        fh[h] = fmaf(vv, w3, fh[h]);
      }
    }
    #pragma unroll
    for (int h = 0; h < 8; ++h) {
      int ab = (int)(unsigned short)(f2bf(ah[h] * LOG2E));
      int fb = ((int)f2bf(fh[h] * LOG2E)) << 16;
      tabI[h * 1024 + c] = fb | ab;                      // head-major for b32 LDS gather
    }
    return;
  }

  int o = blk * 256 + t;
  if (o < 49152) {
    int mat = o >> 14, r = o & 16383;
    int hk = r >> 7, d = r & 127;
    const float* src = (mat == 0) ? Wq : ((mat == 1) ? Wk : Wv);
    Wt[o] = f2bf(src[(hk >> 4) * 2048 + d * 16 + (hk & 15)]);
  } else {
    int o2 = o - 49152;
    int et = o2 >> 11, s = (o2 >> 8) & 7, lane = (o2 >> 2) & 63, i = o2 & 3;
    Wob[o2] = f2bf(Wo[(s * 16 + (lane >> 4) * 4 + i) * 128 + et * 16 + (lane & 15)]);
  }
}

// ---- kernel A: QKV projection via MFMA (unchanged, verified) ----
__global__ __launch_bounds__(256, 4) void qkv4(
    const float* __restrict__ q, const short* __restrict__ Wt,
    short* __restrict__ Qb, short* __restrict__ Kb, short* __restrict__ Vt)
{
  __shared__ short qs[16][136];
  int blk = blockIdx.x;
  int b = blk >> 5;
  int rt = (blk & 31) << 4;
  int t = threadIdx.x;
  int wid = t >> 6, lane = t & 63;
  int lq = lane & 15, lg = lane >> 4;

  #pragma unroll
  for (int it = 0; it < 2; ++it) {
    int u = t + it * 256;
    int row = u >> 5, c4 = (u & 31) << 2;
    float4 v = *(const float4*)&q[((((b << 9) + rt + row) << 7)) + c4];
    *(s16x4*)&qs[row][c4] = pack4(v.x, v.y, v.z, v.w);
  }
  __syncthreads();

  s16x4 af[8];
  #pragma unroll
  for (int ks = 0; ks < 8; ++ks)
    af[ks] = *(const s16x4*)&qs[lq][ks * 16 + lg * 4];

  #pragma unroll 1
  for (int pj = 0; pj < 3; ++pj) {
    const short* Wm = Wt + pj * 16384;
    #pragma unroll
    for (int c2 = 0; c2 < 2; ++c2) {
      int ct = wid * 2 + c2;
      f32x4 acc = (f32x4)0.f;
      #pragma unroll
      for (int ks = 0; ks < 8; ++ks) {
        s16x4 bf = *(const s16x4*)&Wm[(ct * 16 + lq) * 128 + ks * 16 + lg * 4];
        acc = mfma16(af[ks], bf, acc);
      }
      if (pj == 0) {
        s16x4 pk = pack4(acc[0] * (0.25f * LOG2E), acc[1] * (0.25f * LOG2E),
                         acc[2] * (0.25f * LOG2E), acc[3] * (0.25f * LOG2E));
        #pragma unroll
        for (int r = 0; r < 4; ++r)
          Qb[(ct << 18) + (b << 13) + ((rt + lg * 4 + r) << 4) + lq] = pk[r];
      } else if (pj == 1) {
        s16x4 pk = pack4(acc[0], acc[1], acc[2], acc[3]);
        #pragma unroll
        for (int r = 0; r < 4; ++r)
          Kb[(ct << 18) + (b << 13) + ((rt + lg * 4 + r) << 4) + lq] = pk[r];
      } else {
        s16x4 pk = pack4(acc[0], acc[1], acc[2], acc[3]);
        *(s16x4*)&Vt[(ct << 18) + (((b << 4) + lq) << 9) + rt + lg * 4] = pk;
      }
    }
  }
}

// ---- kernel B: 8-wave attn, 8 heads/wave, chunk-PAIR interleaved main loop ----
// 512 threads; wave w owns chunks {w+16*cc, w+16*cc+8 : cc=0,1} (A/B pairs).
// LDS 36864B: tabL int[8][1024] @0 (32KB); epilogue overlay obfL [8w][8h][64] s16x4 @0
// + psL f32[8][8][16] @32768. launch_bounds(512) only — let allocator take VGPRs for ILP
// (r12 lesson: occupancy-chasing at VGPR 32 destroys pipelining; ILP > waves here).
__global__ __launch_bounds__(512) void attn13(
    const float* __restrict__ edge, const unsigned char* __restrict__ maskB,
    const int* __restrict__ flag,
    const short* __restrict__ Qb, const short* __restrict__ Kb, const short* __restrict__ Vt,
    const short* __restrict__ Wob,
    const int* __restrict__ tabI,
    float* __restrict__ out)
{
  __shared__ __align__(16) char smem[36864];

  int t = threadIdx.x;
  int wid = t >> 6, lane = t & 63;
  int lq = lane & 15, lg = lane >> 4;
  int b = blockIdx.x >> 5;
  int qt = (blockIdx.x & 31) << 4;
  int mflag = *flag;

  int* tabL = (int*)smem;                     // [8][1024]
  s16x4* obfL = (s16x4*)smem;                 // [8w][8h][64] overlay
  float* psL = (float*)(smem + 32768);        // [8][8][16]

  for (int u = t; u < 2048; u += 512)
    ((int4*)smem)[u] = ((const int4*)tabI)[u];

  const short* Kl = Kb + (b << 13) + (lq << 4) + (lg << 2);
  const short* Vl = Vt + (((b << 4) + lq) << 9) + (lg << 2);
  const short* Ql = Qb + (b << 13) + ((qt + lq) << 4) + (lg << 2);
  unsigned mbase = (((b << 9) + qt + lq) << 9) + (lg << 2);

  s16x4 qf[8];
  #pragma unroll
  for (int h = 0; h < 8; ++h) qf[h] = *(const s16x4*)(Ql + (h << 18));

  f32x4 oacc[8];
  float psum[8];
  #pragma unroll
  for (int h = 0; h < 8; ++h) { oacc[h] = (f32x4)0.f; psum[h] = 0.f; }

  // prologue: pair 0 (chunks wid and wid+8)
  int jbA = wid << 4, jbB = (wid + 8) << 4;
  float4 evA = *(const float4*)&edge[mbase + jbA];
  float4 evB = *(const float4*)&edge[mbase + jbB];
  int4 mkA, mkB;
  if (mflag) {
    uchar4 ua = *(const uchar4*)&maskB[mbase + jbA];
    uchar4 ub = *(const uchar4*)&maskB[mbase + jbB];
    mkA.x = ua.x; mkA.y = ua.y; mkA.z = ua.z; mkA.w = ua.w;
    mkB.x = ub.x; mkB.y = ub.y; mkB.z = ub.z; mkB.w = ub.w;
  } else {
    mkA = *(const int4*)&((const int*)maskB)[mbase + jbA];
    mkB = *(const int4*)&((const int*)maskB)[mbase + jbB];
  }

  __syncthreads();   // table staged

#define LOOKUP(ev, ix0, ix1, ix2, ix3, em0, em1, em2, em3) { \
    float fx0 = fminf(fmaxf(fmaf(ev.x, 64.f, 512.f), 0.f), 1023.f); \
    float fx1 = fminf(fmaxf(fmaf(ev.y, 64.f, 512.f), 0.f), 1023.f); \
    float fx2 = fminf(fmaxf(fmaf(ev.z, 64.f, 512.f), 0.f), 1023.f); \
    float fx3 = fminf(fmaxf(fmaf(ev.w, 64.f, 512.f), 0.f), 1023.f); \
    ix0 = (int)fx0; ix1 = (int)fx1; ix2 = (int)fx2; ix3 = (int)fx3; \
    em0 = ev.x - fmaf((float)ix0, 0.015625f, -7.9921875f); \
    em1 = ev.y - fmaf((float)ix1, 0.015625f, -7.9921875f); \
    em2 = ev.z - fmaf((float)ix2, 0.015625f, -7.9921875f); \
    em3 = ev.w - fmaf((float)ix3, 0.015625f, -7.9921875f); }

  #pragma unroll 1
  for (int cc = 0; cc < 2; ++cc) {
    jbA = (wid + 16 * cc) << 4;
    jbB = (wid + 16 * cc + 8) << 4;

    int ixA0, ixA1, ixA2, ixA3, ixB0, ixB1, ixB2, ixB3;
    float emA0, emA1, emA2, emA3, emB0, emB1, emB2, emB3;
    LOOKUP(evA, ixA0, ixA1, ixA2, ixA3, emA0, emA1, emA2, emA3)
    LOOKUP(evB, ixB0, ixB1, ixB2, ixB3, emB0, emB1, emB2, emB3)

    // prefetch next pair's edge + mask
    float4 evAn, evBn; int4 mkAn, mkBn;
    if (cc < 1) {
      int jbA2 = (wid + 16) << 4, jbB2 = (wid + 24) << 4;
      evAn = *(const float4*)&edge[mbase + jbA2];
      evBn = *(const float4*)&edge[mbase + jbB2];
      if (mflag) {
        uchar4 ua = *(const uchar4*)&maskB[mbase + jbA2];
        uchar4 ub = *(const uchar4*)&maskB[mbase + jbB2];
        mkAn.x = ua.x; mkAn.y = ua.y; mkAn.z = ua.z; mkAn.w = ua.w;
        mkBn.x = ub.x; mkBn.y = ub.y; mkBn.z = ub.z; mkBn.w = ub.w;
      } else {
        mkAn = *(const int4*)&((const int*)maskB)[mbase + jbA2];
        mkBn = *(const int4*)&((const int*)maskB)[mbase + jbB2];
      }
    } else { evAn = evA; evBn = evB; mkAn = mkA; mkBn = mkB; }

    // per head: two independent chains (A and B sub-chunks)
    #pragma unroll
    for (int h = 0; h < 8; ++h) {
      int a0 = tabL[(h << 10) + ixA0], a1 = tabL[(h << 10) + ixA1];
      int a2 = tabL[(h << 10) + ixA2], a3 = tabL[(h << 10) + ixA3];
      int b0 = tabL[(h << 10) + ixB0], b1 = tabL[(h << 10) + ixB1];
      int b2 = tabL[(h << 10) + ixB2], b3 = tabL[(h << 10) + ixB3];
      s16x4 kfA = *(const s16x4*)(Kl + (h << 18) + (jbA << 4));
      s16x4 kfB = *(const s16x4*)(Kl + (h << 18) + (jbB << 4));
      s16x4 vfA = *(const s16x4*)(Vl + (h << 18) + jbA);
      s16x4 vfB = *(const s16x4*)(Vl + (h << 18) + jbB);
      f32x4 scA, scB;
      scA[0] = fmaf(__int_as_float(a0 << 16), emA0, __int_as_float(a0 & 0xffff0000));
      scA[1] = fmaf(__int_as_float(a1 << 16), emA1, __int_as_float(a1 & 0xffff0000));
      scA[2] = fmaf(__int_as_float(a2 << 16), emA2, __int_as_float(a2 & 0xffff0000));
      scA[3] = fmaf(__int_as_float(a3 << 16), emA3, __int_as_float(a3 & 0xffff0000));
      scB[0] = fmaf(__int_as_float(b0 << 16), emB0, __int_as_float(b0 & 0xffff0000));
      scB[1] = fmaf(__int_as_float(b1 << 16), emB1, __int_as_float(b1 & 0xffff0000));
      scB[2] = fmaf(__int_as_float(b2 << 16), emB2, __int_as_float(b2 & 0xffff0000));
      scB[3] = fmaf(__int_as_float(b3 << 16), emB3, __int_as_float(b3 & 0xffff0000));
      scA = mfma16(kfA, qf[h], scA);
      scB = mfma16(kfB, qf[h], scB);
      float pA0 = mkA.x ? 0.f : EXP2F(fminf(scA[0], SCLAMP));
      float pA1 = mkA.y ? 0.f : EXP2F(fminf(scA[1], SCLAMP));
      float pA2 = mkA.z ? 0.f : EXP2F(fminf(scA[2], SCLAMP));
      float pA3 = mkA.w ? 0.f : EXP2F(fminf(scA[3], SCLAMP));
      float pB0 = mkB.x ? 0.f : EXP2F(fminf(scB[0], SCLAMP));
      float pB1 = mkB.y ? 0.f : EXP2F(fminf(scB[1], SCLAMP));
      float pB2 = mkB.z ? 0.f : EXP2F(fminf(scB[2], SCLAMP));
      float pB3 = mkB.w ? 0.f : EXP2F(fminf(scB[3], SCLAMP));
      psum[h] += ((pA0 + pA1) + (pA2 + pA3)) + ((pB0 + pB1) + (pB2 + pB3));
      s16x4 pfA = pack4(pA0, pA1, pA2, pA3);
      s16x4 pfB = pack4(pB0, pB1, pB2, pB3);
      oacc[h] = mfma16(vfA, pfA, oacc[h]);
      oacc[h] = mfma16(vfB, pfB, oacc[h]);
    }
    evA = evAn; evB = evBn; mkA = mkAn; mkB = mkBn;
  }
#undef LOOKUP

  // ---- epilogue (identical to verified r11) ----
  #pragma unroll
  for (int h = 0; h < 8; ++h) {
    float s = psum[h];
    s += __shfl_xor(s, 16);
    s += __shfl_xor(s, 32);
    psum[h] = s;
  }
  if (lg == 0) {
    #pragma unroll
    for (int h = 0; h < 8; ++h) psL[(wid << 7) + (h << 4) + lq] = psum[h];
  }
  __syncthreads();   // all waves done with main loop (table now dead)

  #pragma unroll
  for (int h = 0; h < 8; ++h) {
    float tot = 0.f;
    #pragma unroll
    for (int w2 = 0; w2 < 8; ++w2) tot += psL[(w2 << 7) + (h << 4) + lq];
    float inv = (tot > 0.f) ? 1.f / tot : 0.f;
    obfL[((wid << 3) + h << 6) + lane] =
        pack4(oacc[h][0] * inv, oacc[h][1] * inv, oacc[h][2] * inv, oacc[h][3] * inv);
  }
  __syncthreads();

  {
    f32x4 d2a = (f32x4)0.f;
    #pragma unroll
    for (int s = 0; s < 8; ++s) {
      f32x4 fa = (f32x4)0.f;
      #pragma unroll
      for (int w2 = 0; w2 < 8; ++w2) {
        union { s16x4 v; int i[2]; } bb;
        bb.v = obfL[((w2 << 3) + s << 6) + lane];
        fa[0] += __int_as_float(bb.i[0] << 16);
        fa[1] += __int_as_float(bb.i[0] & 0xffff0000);
        fa[2] += __int_as_float(bb.i[1] << 16);
        fa[3] += __int_as_float(bb.i[1] & 0xffff0000);
      }
      s16x4 ob = pack4(fa[0], fa[1], fa[2], fa[3]);
      s16x4 wo = *(const s16x4*)&Wob[(((wid << 3) + s) << 8) + (lane << 2)];
      d2a = mfma16(wo, ob, d2a);
    }
    *(float4*)&out[((((b << 9) + qt + lq) << 7)) + (wid << 4) + (lg << 2)] =
        *(float4*)&d2a;
  }
}

extern "C" void kernel_launch(void* const* d_in, const int* in_sizes, int n_in,
                              void* d_out, int out_size, void* d_ws, size_t ws_size,
                              hipStream_t stream)
{
  const float* q    = (const float*)d_in[0];
  const unsigned char* mask = (const unsigned char*)d_in[1];
  const float* edge = (const float*)d_in[2];
  const float* Wq   = (const float*)d_in[3];
  const float* Wk   = (const float*)d_in[4];
  const float* Wv   = (const float*)d_in[5];
  const float* Wo   = (const float*)d_in[6];
  const float* mW1  = (const float*)d_in[7];
  const float* mb1  = (const float*)d_in[8];
  const float* mW2  = (const float*)d_in[9];
  const float* mb2  = (const float*)d_in[10];
  const float* mW3  = (const float*)d_in[11];
  const float* mb3  = (const float*)d_in[12];
  float* out = (float*)d_out;

  size_t per = (size_t)Hc * Bc * Nc * DKc;     // 2,097,152 bf16 elems per matrix
  short* Wt  = (short*)d_ws;                   // 49152
  short* Wob = Wt + 49152;                     // 16384
  short* Qb  = Wob + 16384;
  short* Kb  = Qb + per;
  short* Vt  = Kb + per;
  int* tabI  = (int*)(Vt + per);               // 8192 ints (32 KB), 16B-aligned
  int* flag  = tabI + 8192;                    // ~12.7 MB used

  prep_all<<<dim3(261), dim3(256), 0, stream>>>(Wq, Wk, Wv, Wo, mask, flag,
      mW1, mb1, mW2, mb2, mW3, mb3, Wt, Wob, tabI);
  qkv4<<<dim3(Bc * 32), dim3(256), 0, stream>>>(q, Wt, Qb, Kb, Vt);
  attn13<<<dim3(Bc * 32), dim3(512), 0, stream>>>(edge, mask, flag, Qb, Kb, Vt, Wob,
      tabI, out);
}